// Round 6
// baseline (479.149 us; speedup 1.0000x reference)
//
#include <hip/hip_runtime.h>

// DEQ fully register-resident, zero-LDS-storage, zero-barrier:
//   out = relu^{(30)}(z Wz^T + inj) @ Wd^T + bd,  inj = x Ux^T + b
//
// Each WAVE owns 16 batch rows and the FULL 128-wide hidden state:
//   D[n][m] = sum_k Wz[n][k] * z^T[k][m], n = 0..127 (8 MFMA tiles), m = l15.
// Wz lives in 128 regs/lane (unified VGPR+AGPR file). z is re-fed to the next
// iteration's B-operand entirely in-register (exchange algebra HW-verified
// rounds 1/5; permlane16 variant FAILED round 4 — do not reintroduce):
//   D layout: lane(q,l) holds n = 16t + 4q + i  (i = reg 0..3)
//   B layout: lane(q,l) needs k = 32ks + 8q + j (j = 0..7)
//   t-parity split: v_permlane32_swap; lane^16: ds_swizzle 0x401F.
//
// Round-6 change vs round 5 (same math, new SCHEDULE):
//   - all 8 ds_swizzles issued in one burst at iteration top (one shared
//     ~120cy LDS latency instead of 4 sequential per-frag waits)
//   - MFMA phase t-major with relu/pack fused per tile (VALU pack of tile t
//     overlaps matrix-pipe issue of tiles t+1..7)
//   - s_setprio(1) around the MFMA phase (independent phase-staggered waves
//     = the regime where setprio pays, per T5)
// Round 5 measured: 390us, MfmaUtil 28.5, occ 21.8 (2 waves/SIMD, 248 regs).
// Per-wave iter = ~3900cy vs 620cy MFMA demand -> latency-bound schedule.

typedef __attribute__((ext_vector_type(8))) __bf16 bf16x8;
typedef __attribute__((ext_vector_type(2))) __bf16 bf16x2;
typedef __attribute__((ext_vector_type(4))) float  floatx4;

#define MFMA16(a, b, c) __builtin_amdgcn_mfma_f32_16x16x32_bf16((a), (b), (c), 0, 0, 0)

static constexpr int kBsz = 262144;

__device__ __forceinline__ bf16x8 cvt_bf16x8(float4 a, float4 b) {
  bf16x8 r;
  r[0] = (__bf16)a.x; r[1] = (__bf16)a.y; r[2] = (__bf16)a.z; r[3] = (__bf16)a.w;
  r[4] = (__bf16)b.x; r[5] = (__bf16)b.y; r[6] = (__bf16)b.z; r[7] = (__bf16)b.w;
  return r;
}

__device__ __forceinline__ unsigned pk_relu2(float a, float b) {
  union { bf16x2 h; unsigned u; } x;
  x.h[0] = (__bf16)fmaxf(a, 0.0f);
  x.h[1] = (__bf16)fmaxf(b, 0.0f);
  return x.u;
}

union Frag { bf16x8 v; unsigned w[4]; };

// Reference single-shot frag builder (used in prologue-free paths: decoder).
// Identical algebra to the pipelined loop body below; HW-verified round 1/5.
__device__ __forceinline__ bf16x8 build_frag(unsigned ulo, unsigned vlo,
                                             unsigned uhi, unsigned vhi,
                                             bool qodd) {
  asm("v_permlane32_swap_b32 %0, %1" : "+v"(ulo), "+v"(vlo));
  asm("v_permlane32_swap_b32 %0, %1" : "+v"(uhi), "+v"(vhi));
  const unsigned c0 = qodd ? vlo : ulo;
  const unsigned d0 = qodd ? ulo : vlo;
  const unsigned c1 = qodd ? vhi : uhi;
  const unsigned d1 = qodd ? uhi : vhi;
  const unsigned dx0 = __builtin_amdgcn_ds_swizzle((int)d0, 0x401F); // lane^16
  const unsigned dx1 = __builtin_amdgcn_ds_swizzle((int)d1, 0x401F);
  Frag f;
  f.w[0] = qodd ? dx0 : c0;
  f.w[1] = qodd ? dx1 : c1;
  f.w[2] = qodd ? c0 : dx0;
  f.w[3] = qodd ? c1 : dx1;
  return f.v;
}

__global__ void __launch_bounds__(256, 2) deq_fused(
    const float* __restrict__ x,    // [B,64]
    const float* __restrict__ Wz,   // [128,128]
    const float* __restrict__ Ux,   // [128,64]
    const float* __restrict__ bvec, // [128]
    const float* __restrict__ Wd,   // [64,128]
    const float* __restrict__ bd,   // [64]
    const int*  __restrict__ n_iters_p,
    float* __restrict__ out)        // [B,64]
{
  const int tid  = threadIdx.x;
  const int lane = tid & 63;
  const int wv   = tid >> 6;          // 0..3, independent waves
  const int l15  = lane & 15;
  const int quad = lane >> 4;         // 0..3
  const bool qodd = (quad & 1) != 0;
  const int  mrow = blockIdx.x * 64 + wv * 16 + l15;  // this lane's batch row
  const int  iters = *n_iters_p;

  // ---- inj[t] in C/D layout: reg i -> n = 16t + 4q + i, col m = l15 ----
  floatx4 inj[8];
#pragma unroll
  for (int t = 0; t < 8; ++t) {
    const float4 bv = *(const float4*)(bvec + 16 * t + 4 * quad);
    floatx4 v = {bv.x, bv.y, bv.z, bv.w};
    inj[t] = v;
  }
  {
    // x^T as B-frags (K=64 -> 2 k-chunks)
    bf16x8 bx[2];
#pragma unroll
    for (int ks = 0; ks < 2; ++ks) {
      const float4* p = (const float4*)(x + (size_t)mrow * 64 + 32 * ks + 8 * quad);
      bx[ks] = cvt_bf16x8(p[0], p[1]);
    }
#pragma unroll
    for (int t = 0; t < 8; ++t) {
#pragma unroll
      for (int ks = 0; ks < 2; ++ks) {
        const float4* p = (const float4*)(Ux + (16 * t + l15) * 64 + 32 * ks + 8 * quad);
        const bf16x8 a = cvt_bf16x8(p[0], p[1]);
        inj[t] = MFMA16(a, bx[ks], inj[t]);
      }
    }
  }

  // ---- Wz as A-frags, full 128x128, register/AGPR-resident (128 regs) ----
  bf16x8 awz[8][4];
#pragma unroll
  for (int t = 0; t < 8; ++t)
#pragma unroll
    for (int ks = 0; ks < 4; ++ks) {
      const float4* p = (const float4*)(Wz + (16 * t + l15) * 128 + 32 * ks + 8 * quad);
      awz[t][ks] = cvt_bf16x8(p[0], p[1]);
    }

  // ---- z1 = relu(inj) packed: lo = (i0,i1), hi = (i2,i3) per tile ----
  unsigned lo[8], hi[8];
#pragma unroll
  for (int t = 0; t < 8; ++t) {
    lo[t] = pk_relu2(inj[t][0], inj[t][1]);
    hi[t] = pk_relu2(inj[t][2], inj[t][3]);
  }

  // ---- fixed-point loop: pipelined schedule ----
  for (int it = 0; it < iters - 1; ++it) {
    // Phase 1: exchange issue — permlane swaps + selects, then ALL 8
    // ds_swizzles in one burst (independent, one shared latency).
    unsigned c0[4], c1[4], dx0[4], dx1[4];
#pragma unroll
    for (int ks = 0; ks < 4; ++ks) {
      unsigned ulo = lo[2 * ks], vlo = lo[2 * ks + 1];
      unsigned uhi = hi[2 * ks], vhi = hi[2 * ks + 1];
      asm("v_permlane32_swap_b32 %0, %1" : "+v"(ulo), "+v"(vlo));
      asm("v_permlane32_swap_b32 %0, %1" : "+v"(uhi), "+v"(vhi));
      c0[ks] = qodd ? vlo : ulo;
      c1[ks] = qodd ? vhi : uhi;
      dx0[ks] = __builtin_amdgcn_ds_swizzle((int)(qodd ? ulo : vlo), 0x401F);
      dx1[ks] = __builtin_amdgcn_ds_swizzle((int)(qodd ? uhi : vhi), 0x401F);
    }
    // Phase 2: final frag selects.
    bf16x8 f[4];
#pragma unroll
    for (int ks = 0; ks < 4; ++ks) {
      Frag fr;
      fr.w[0] = qodd ? dx0[ks] : c0[ks];
      fr.w[1] = qodd ? dx1[ks] : c1[ks];
      fr.w[2] = qodd ? c0[ks] : dx0[ks];
      fr.w[3] = qodd ? c1[ks] : dx1[ks];
      f[ks] = fr.v;
    }
    // Phase 3: MFMA t-major; pack of tile t overlaps MFMAs of tiles t+1..7.
    __builtin_amdgcn_s_setprio(1);
#pragma unroll
    for (int t = 0; t < 8; ++t) {
      floatx4 acc = MFMA16(awz[t][0], f[0], inj[t]);  // C-in = inj, no copies
      acc = MFMA16(awz[t][1], f[1], acc);
      acc = MFMA16(awz[t][2], f[2], acc);
      acc = MFMA16(awz[t][3], f[3], acc);
      lo[t] = pk_relu2(acc[0], acc[1]);
      hi[t] = pk_relu2(acc[2], acc[3]);
    }
    __builtin_amdgcn_s_setprio(0);
  }

  // ---- decoder: D[o][m] = sum_k Wd[o][k] z^T[k][m] + bd ----
  bf16x8 bz[4];
#pragma unroll
  for (int ks = 0; ks < 4; ++ks)
    bz[ks] = build_frag(lo[2 * ks], lo[2 * ks + 1],
                        hi[2 * ks], hi[2 * ks + 1], qodd);
#pragma unroll
  for (int ot = 0; ot < 4; ++ot) {
    const float4 bv = *(const float4*)(bd + 16 * ot + 4 * quad);
    floatx4 acc = {bv.x, bv.y, bv.z, bv.w};
#pragma unroll
    for (int ks = 0; ks < 4; ++ks) {
      const float4* p = (const float4*)(Wd + (16 * ot + l15) * 128 + 32 * ks + 8 * quad);
      const bf16x8 a = cvt_bf16x8(p[0], p[1]);
      acc = MFMA16(a, bz[ks], acc);
    }
    float4 ov;
    ov.x = acc[0]; ov.y = acc[1]; ov.z = acc[2]; ov.w = acc[3];
    *(float4*)(out + (size_t)mrow * 64 + 16 * ot + 4 * quad) = ov;
  }
}

extern "C" void kernel_launch(void* const* d_in, const int* in_sizes, int n_in,
                              void* d_out, int out_size, void* d_ws, size_t ws_size,
                              hipStream_t stream) {
  const float* x  = (const float*)d_in[0];
  const float* Wz = (const float*)d_in[1];
  const float* Ux = (const float*)d_in[2];
  const float* b  = (const float*)d_in[3];
  const float* Wd = (const float*)d_in[4];
  const float* bd = (const float*)d_in[5];
  const int* n_it = (const int*)d_in[6];
  float* outp = (float*)d_out;
  (void)in_sizes; (void)n_in; (void)d_ws; (void)ws_size; (void)out_size;

  dim3 grid(kBsz / 64);  // 4096 blocks x 4 independent waves, 16 rows/wave
  deq_fused<<<grid, 256, 0, stream>>>(x, Wz, Ux, b, Wd, bd, n_it, outp);
}

// Round 7
// 357.779 us; speedup vs baseline: 1.3392x; 1.3392x over previous
//
#include <hip/hip_runtime.h>

// DEQ fused: out = relu^{(30)}(z Wz^T + inj) @ Wd^T + bd, inj = x Ux^T + b
//
// Round-0 verified structure (LDS z-exchange, double buffer, 1 barrier/iter,
// 16x16x32 MFMA, padded stride-136 tile) with ONE change: 128-thread blocks
// (2 waves, 32 rows) instead of 256-thread blocks (4 waves, 64 rows).
//   - per-wave work identical (n-half x 2 m-tiles x 4 k-steps = 32 MFMA/iter)
//   - LDS per block 34.8 KB -> 17.4 KB  => up to 9 resident blocks/CU vs 2.5
//   - barrier couples 2 waves, and 9 independent barrier groups per CU hide
//     each other's barrier+LDS latency (round 0's diagnosed limiter: block-iter
//     latency ~1375cy vs 512cy MFMA demand, only 2.5 independent chains).
// Register-resident family (rounds 1-6) is a dead end: 128 Wz regs/wave caps
// occupancy at 2 waves/SIMD -> 390us floor. This buys latency hiding with
// occupancy instead of registers.

typedef __attribute__((ext_vector_type(8))) __bf16 bf16x8;
typedef __attribute__((ext_vector_type(4))) __bf16 bf16x4;
typedef __attribute__((ext_vector_type(4))) float  floatx4;

#define MFMA16(a, b, c) __builtin_amdgcn_mfma_f32_16x16x32_bf16((a), (b), (c), 0, 0, 0)

static constexpr int kBsz = 262144;
static constexpr int kTM  = 32;    // batch rows per block

__device__ __forceinline__ bf16x8 cvt_bf16x8(float4 a, float4 b) {
  bf16x8 r;
  r[0] = (__bf16)a.x; r[1] = (__bf16)a.y; r[2] = (__bf16)a.z; r[3] = (__bf16)a.w;
  r[4] = (__bf16)b.x; r[5] = (__bf16)b.y; r[6] = (__bf16)b.z; r[7] = (__bf16)b.w;
  return r;
}

__global__ void __launch_bounds__(128) deq_fused(
    const float* __restrict__ x,    // [B,64]
    const float* __restrict__ Wz,   // [128,128]
    const float* __restrict__ Ux,   // [128,64]
    const float* __restrict__ bvec, // [128]
    const float* __restrict__ Wd,   // [64,128]
    const float* __restrict__ bd,   // [64]
    const int*  __restrict__ n_iters_p,
    float* __restrict__ out)        // [B,64]
{
  // double-buffered z tile, row-major [m][n], stride 136 bf16 = 272 B
  // (272 B = 68 words -> 4m mod 32 bank spread, 2-way conflicts only = free)
  __shared__ __align__(16) __bf16 zl[2][kTM][136];   // 17408 B

  const int tid  = threadIdx.x;
  const int lane = tid & 63;
  const int wn   = tid >> 6;   // 0..1, n-half: hid units [64*wn, 64*wn+64)
  const int l15  = lane & 15;
  const int quad = lane >> 4;  // 0..3
  const int row0 = blockIdx.x * kTM;
  const int iters = *n_iters_p;

  // ---- Wz as A-fragments (iteration-invariant, register-resident) ----
  // A[n][k]: n = 64*wn + 16*nt + l15, k = 32*ks + 8*quad + j
  bf16x8 awz[4][4];
#pragma unroll
  for (int nt = 0; nt < 4; ++nt) {
    const int n = 64 * wn + 16 * nt + l15;
#pragma unroll
    for (int ks = 0; ks < 4; ++ks) {
      const float4* p = (const float4*)(Wz + n * 128 + 32 * ks + 8 * quad);
      awz[nt][ks] = cvt_bf16x8(p[0], p[1]);
    }
  }

  // ---- inj^T in C/D layout: inj[nt][mt], reg i -> n = 64wn+16nt+4quad+i ----
  floatx4 inj[4][2];
#pragma unroll
  for (int nt = 0; nt < 4; ++nt) {
    const float4 bv = *(const float4*)(bvec + 64 * wn + 16 * nt + 4 * quad);
#pragma unroll
    for (int mt = 0; mt < 2; ++mt) {
      floatx4 v = {bv.x, bv.y, bv.z, bv.w};
      inj[nt][mt] = v;
    }
  }
  {
    // Ux as A-frags (K=64 -> 2 k-steps)
    bf16x8 aux[4][2];
#pragma unroll
    for (int nt = 0; nt < 4; ++nt) {
      const int n = 64 * wn + 16 * nt + l15;
#pragma unroll
      for (int ks = 0; ks < 2; ++ks) {
        const float4* p = (const float4*)(Ux + n * 64 + 32 * ks + 8 * quad);
        aux[nt][ks] = cvt_bf16x8(p[0], p[1]);
      }
    }
    // x^T as B-frags: B[k][m] = x[m][k]
#pragma unroll
    for (int mt = 0; mt < 2; ++mt) {
      const int m = row0 + 16 * mt + l15;
#pragma unroll
      for (int ks = 0; ks < 2; ++ks) {
        const float4* p = (const float4*)(x + m * 64 + 32 * ks + 8 * quad);
        const bf16x8 bx = cvt_bf16x8(p[0], p[1]);
#pragma unroll
        for (int nt = 0; nt < 4; ++nt)
          inj[nt][mt] = MFMA16(aux[nt][ks], bx, inj[nt][mt]);
      }
    }
  }

  // ---- z1 = relu(inj) (z0 = 0) -> buffer 0, packed b64 writes ----
#pragma unroll
  for (int mt = 0; mt < 2; ++mt) {
    const int ml = 16 * mt + l15;
#pragma unroll
    for (int nt = 0; nt < 4; ++nt) {
      bf16x4 z4;
#pragma unroll
      for (int i = 0; i < 4; ++i) z4[i] = (__bf16)fmaxf(inj[nt][mt][i], 0.0f);
      *(bf16x4*)&zl[0][ml][64 * wn + 16 * nt + 4 * quad] = z4;
    }
  }

  // ---- fixed-point loop: 1 barrier per iteration (double buffer) ----
  int pb = 0;
  for (int t = 0; t < iters - 1; ++t) {
    __syncthreads();
    // prefetch Z^T B-frags: B[k][m], k contiguous -> ds_read_b128
    bf16x8 bz[2][4];
#pragma unroll
    for (int mt = 0; mt < 2; ++mt) {
      const int ml = 16 * mt + l15;
#pragma unroll
      for (int ks = 0; ks < 4; ++ks)
        bz[mt][ks] = *(const bf16x8*)&zl[pb][ml][32 * ks + 8 * quad];
    }
    const int nb = pb ^ 1;
#pragma unroll
    for (int mt = 0; mt < 2; ++mt) {
      const int ml = 16 * mt + l15;
#pragma unroll
      for (int nt = 0; nt < 4; ++nt) {
        floatx4 acc = inj[nt][mt];
#pragma unroll
        for (int ks = 0; ks < 4; ++ks)
          acc = MFMA16(awz[nt][ks], bz[mt][ks], acc);
        bf16x4 z4;
#pragma unroll
        for (int i = 0; i < 4; ++i) z4[i] = (__bf16)fmaxf(acc[i], 0.0f);
        // reg axis i is consecutive n -> one ds_write_b64
        *(bf16x4*)&zl[nb][ml][64 * wn + 16 * nt + 4 * quad] = z4;
      }
    }
    pb = nb;
  }
  __syncthreads();

  // ---- decoder: D[o][m] = sum_k Wd[o][k] Z^T[k][m] + bd ----
  bf16x8 awd[2][4];
#pragma unroll
  for (int ot = 0; ot < 2; ++ot) {
    const int o = 32 * wn + 16 * ot + l15;
#pragma unroll
    for (int ks = 0; ks < 4; ++ks) {
      const float4* p = (const float4*)(Wd + o * 128 + 32 * ks + 8 * quad);
      awd[ot][ks] = cvt_bf16x8(p[0], p[1]);
    }
  }
#pragma unroll
  for (int mt = 0; mt < 2; ++mt) {
    const int ml = 16 * mt + l15;
    bf16x8 bz[4];
#pragma unroll
    for (int ks = 0; ks < 4; ++ks)
      bz[ks] = *(const bf16x8*)&zl[pb][ml][32 * ks + 8 * quad];
#pragma unroll
    for (int ot = 0; ot < 2; ++ot) {
      const float4 bv = *(const float4*)(bd + 32 * wn + 16 * ot + 4 * quad);
      floatx4 acc = {bv.x, bv.y, bv.z, bv.w};
#pragma unroll
      for (int ks = 0; ks < 4; ++ks)
        acc = MFMA16(awd[ot][ks], bz[ks], acc);
      // reg i -> consecutive o: one dwordx4 global store
      float4 ov;
      ov.x = acc[0]; ov.y = acc[1]; ov.z = acc[2]; ov.w = acc[3];
      *(float4*)(out + (size_t)(row0 + ml) * 64 + 32 * wn + 16 * ot + 4 * quad) = ov;
    }
  }
}

extern "C" void kernel_launch(void* const* d_in, const int* in_sizes, int n_in,
                              void* d_out, int out_size, void* d_ws, size_t ws_size,
                              hipStream_t stream) {
  const float* x  = (const float*)d_in[0];
  const float* Wz = (const float*)d_in[1];
  const float* Ux = (const float*)d_in[2];
  const float* b  = (const float*)d_in[3];
  const float* Wd = (const float*)d_in[4];
  const float* bd = (const float*)d_in[5];
  const int* n_it = (const int*)d_in[6];
  float* outp = (float*)d_out;
  (void)in_sizes; (void)n_in; (void)d_ws; (void)ws_size; (void)out_size;

  dim3 grid(kBsz / kTM);  // 8192 blocks of 128 threads
  deq_fused<<<grid, 128, 0, stream>>>(x, Wz, Ux, b, Wd, bd, n_it, outp);
}

// Round 8
// 334.488 us; speedup vs baseline: 1.4325x; 1.0696x over previous
//
#include <hip/hip_runtime.h>

// DEQ fused: out = relu^{(30)}(z Wz^T + inj) @ Wd^T + bd, inj = x Ux^T + b
//
// Round-8: occupancy bought with registers. Rounds 0/7 proved the structure is
// register-bound at ~205 unified regs/wave (76 VGPR + ~128 AGPR: awz 64 +
// acc 32 + inj 32) -> 2.5 waves/SIMD -> 42% MfmaUtil regardless of layout.
// This version gives each of 4 waves a 32-wide n-QUARTER (awz = 32 regs) over
// the block's 32 rows:
//   per wave/iter: 2nt x 2mt x 4ks = 16 MFMA; regs ~111 -> 4 waves/SIMD
//   (launch_bounds(256,4) caps unified file at 128).
// Cost: LDS read amplification 4x (each wave reads full k=128 for its rows):
// 32KB reads + 8KB writes per block-iter -> LDS pipe ~ matrix pipe ~ 300k
// cy/CU, but they are DIFFERENT pipes and 16 waves/CU now overlap them.
// SQ_LDS_BANK_CONFLICT == #b128_reads * 8 (inherent wave64 phasing, benign;
// invariant across padded/swizzled layouts in rounds 0/2/7).

typedef __attribute__((ext_vector_type(8))) __bf16 bf16x8;
typedef __attribute__((ext_vector_type(4))) __bf16 bf16x4;
typedef __attribute__((ext_vector_type(4))) float  floatx4;

#define MFMA16(a, b, c) __builtin_amdgcn_mfma_f32_16x16x32_bf16((a), (b), (c), 0, 0, 0)

static constexpr int kBsz = 262144;
static constexpr int kTM  = 32;    // batch rows per block

__device__ __forceinline__ bf16x8 cvt_bf16x8(float4 a, float4 b) {
  bf16x8 r;
  r[0] = (__bf16)a.x; r[1] = (__bf16)a.y; r[2] = (__bf16)a.z; r[3] = (__bf16)a.w;
  r[4] = (__bf16)b.x; r[5] = (__bf16)b.y; r[6] = (__bf16)b.z; r[7] = (__bf16)b.w;
  return r;
}

__global__ void __launch_bounds__(256, 4) deq_fused(
    const float* __restrict__ x,    // [B,64]
    const float* __restrict__ Wz,   // [128,128]
    const float* __restrict__ Ux,   // [128,64]
    const float* __restrict__ bvec, // [128]
    const float* __restrict__ Wd,   // [64,128]
    const float* __restrict__ bd,   // [64]
    const int*  __restrict__ n_iters_p,
    float* __restrict__ out)        // [B,64]
{
  // double-buffered z tile, row-major [m][n], stride 136 bf16 = 272 B
  __shared__ __align__(16) __bf16 zl[2][kTM][136];   // 17408 B

  const int tid  = threadIdx.x;
  const int lane = tid & 63;
  const int wv   = tid >> 6;   // 0..3: n-quarter [32*wv, 32*wv+32)
  const int l15  = lane & 15;
  const int quad = lane >> 4;  // 0..3
  const int row0 = blockIdx.x * kTM;
  const int iters = *n_iters_p;

  // ---- Wz as A-fragments (iteration-invariant, 32 regs) ----
  // A[n][k]: n = 32*wv + 16*nt + l15, k = 32*ks + 8*quad + j
  bf16x8 awz[2][4];
#pragma unroll
  for (int nt = 0; nt < 2; ++nt) {
    const int n = 32 * wv + 16 * nt + l15;
#pragma unroll
    for (int ks = 0; ks < 4; ++ks) {
      const float4* p = (const float4*)(Wz + n * 128 + 32 * ks + 8 * quad);
      awz[nt][ks] = cvt_bf16x8(p[0], p[1]);
    }
  }

  // ---- inj^T in C/D layout: inj[nt][mt], reg i -> n = 32wv+16nt+4quad+i ----
  floatx4 inj[2][2];
#pragma unroll
  for (int nt = 0; nt < 2; ++nt) {
    const float4 bv = *(const float4*)(bvec + 32 * wv + 16 * nt + 4 * quad);
#pragma unroll
    for (int mt = 0; mt < 2; ++mt) {
      floatx4 v = {bv.x, bv.y, bv.z, bv.w};
      inj[nt][mt] = v;
    }
  }
  {
    // Ux as A-frags (K=64 -> 2 k-steps)
    bf16x8 aux[2][2];
#pragma unroll
    for (int nt = 0; nt < 2; ++nt) {
      const int n = 32 * wv + 16 * nt + l15;
#pragma unroll
      for (int ks = 0; ks < 2; ++ks) {
        const float4* p = (const float4*)(Ux + n * 64 + 32 * ks + 8 * quad);
        aux[nt][ks] = cvt_bf16x8(p[0], p[1]);
      }
    }
    // x^T as B-frags: B[k][m] = x[m][k]
#pragma unroll
    for (int mt = 0; mt < 2; ++mt) {
      const int m = row0 + 16 * mt + l15;
#pragma unroll
      for (int ks = 0; ks < 2; ++ks) {
        const float4* p = (const float4*)(x + m * 64 + 32 * ks + 8 * quad);
        const bf16x8 bx = cvt_bf16x8(p[0], p[1]);
#pragma unroll
        for (int nt = 0; nt < 2; ++nt)
          inj[nt][mt] = MFMA16(aux[nt][ks], bx, inj[nt][mt]);
      }
    }
  }

  // ---- z1 = relu(inj) (z0 = 0) -> buffer 0, packed b64 writes ----
#pragma unroll
  for (int mt = 0; mt < 2; ++mt) {
    const int ml = 16 * mt + l15;
#pragma unroll
    for (int nt = 0; nt < 2; ++nt) {
      bf16x4 z4;
#pragma unroll
      for (int i = 0; i < 4; ++i) z4[i] = (__bf16)fmaxf(inj[nt][mt][i], 0.0f);
      *(bf16x4*)&zl[0][ml][32 * wv + 16 * nt + 4 * quad] = z4;
    }
  }

  // ---- fixed-point loop: 1 barrier per iteration (double buffer) ----
  int pb = 0;
  for (int t = 0; t < iters - 1; ++t) {
    __syncthreads();
    // full-k B-frags for this wave's rows: 8 x ds_read_b128, one burst
    bf16x8 bz[2][4];
#pragma unroll
    for (int mt = 0; mt < 2; ++mt) {
      const int ml = 16 * mt + l15;
#pragma unroll
      for (int ks = 0; ks < 4; ++ks)
        bz[mt][ks] = *(const bf16x8*)&zl[pb][ml][32 * ks + 8 * quad];
    }
    const int nb = pb ^ 1;
#pragma unroll
    for (int mt = 0; mt < 2; ++mt) {
      const int ml = 16 * mt + l15;
#pragma unroll
      for (int nt = 0; nt < 2; ++nt) {
        floatx4 acc = inj[nt][mt];
#pragma unroll
        for (int ks = 0; ks < 4; ++ks)
          acc = MFMA16(awz[nt][ks], bz[mt][ks], acc);
        bf16x4 z4;
#pragma unroll
        for (int i = 0; i < 4; ++i) z4[i] = (__bf16)fmaxf(acc[i], 0.0f);
        // reg axis i is consecutive n -> one ds_write_b64
        *(bf16x4*)&zl[nb][ml][32 * wv + 16 * nt + 4 * quad] = z4;
      }
    }
    pb = nb;
  }
  __syncthreads();

  // ---- decoder: D[o][m] = sum_k Wd[o][k] Z^T[k][m] + bd ----
  // wave -> (o-half, m-tile): o_half = wv&1, m-tile = wv>>1
  const int oh = wv & 1;
  const int ml = 16 * (wv >> 1) + l15;
  bf16x8 awd[2][4];
#pragma unroll
  for (int ot = 0; ot < 2; ++ot) {
    const int o = 32 * oh + 16 * ot + l15;
#pragma unroll
    for (int ks = 0; ks < 4; ++ks) {
      const float4* p = (const float4*)(Wd + o * 128 + 32 * ks + 8 * quad);
      awd[ot][ks] = cvt_bf16x8(p[0], p[1]);
    }
  }
  {
    bf16x8 bz[4];
#pragma unroll
    for (int ks = 0; ks < 4; ++ks)
      bz[ks] = *(const bf16x8*)&zl[pb][ml][32 * ks + 8 * quad];
#pragma unroll
    for (int ot = 0; ot < 2; ++ot) {
      const float4 bv = *(const float4*)(bd + 32 * oh + 16 * ot + 4 * quad);
      floatx4 acc = {bv.x, bv.y, bv.z, bv.w};
#pragma unroll
      for (int ks = 0; ks < 4; ++ks)
        acc = MFMA16(awd[ot][ks], bz[ks], acc);
      // reg i -> consecutive o: one dwordx4 global store
      float4 ov;
      ov.x = acc[0]; ov.y = acc[1]; ov.z = acc[2]; ov.w = acc[3];
      *(float4*)(out + (size_t)(row0 + ml) * 64 + 32 * oh + 16 * ot + 4 * quad) = ov;
    }
  }
}

extern "C" void kernel_launch(void* const* d_in, const int* in_sizes, int n_in,
                              void* d_out, int out_size, void* d_ws, size_t ws_size,
                              hipStream_t stream) {
  const float* x  = (const float*)d_in[0];
  const float* Wz = (const float*)d_in[1];
  const float* Ux = (const float*)d_in[2];
  const float* b  = (const float*)d_in[3];
  const float* Wd = (const float*)d_in[4];
  const float* bd = (const float*)d_in[5];
  const int* n_it = (const int*)d_in[6];
  float* outp = (float*)d_out;
  (void)in_sizes; (void)n_in; (void)d_ws; (void)ws_size; (void)out_size;

  dim3 grid(kBsz / kTM);  // 8192 blocks of 256 threads
  deq_fused<<<grid, 256, 0, stream>>>(x, Wz, Ux, b, Wd, bd, n_it, outp);
}